// Round 2
// baseline (886.058 us; speedup 1.0000x reference)
//
#include <hip/hip_runtime.h>

typedef __bf16 bf16x8 __attribute__((ext_vector_type(8)));
typedef float  f32x4  __attribute__((ext_vector_type(4)));

#define N_NODES   1000000
#define N_GRAPHS  16384
#define CAPX      128     // x rows cached in LDS per graph
#define CAPS      768     // scores/attn cached in LDS per graph
#define NEG_INF  (-3.0e38f)

__device__ __forceinline__ unsigned short f2bfu(float f) {
  union { __bf16 h; unsigned short u; } c; c.h = (__bf16)f; return c.u;
}
__device__ __forceinline__ float bfu2f(unsigned short us) {
  union { unsigned u; float f; } c; c.u = ((unsigned)us) << 16; return c.f;
}
__device__ __forceinline__ bf16x8 pack8(const float4 a, const float4 b) {
  bf16x8 r;
  r[0] = (__bf16)a.x; r[1] = (__bf16)a.y; r[2] = (__bf16)a.z; r[3] = (__bf16)a.w;
  r[4] = (__bf16)b.x; r[5] = (__bf16)b.y; r[6] = (__bf16)b.z; r[7] = (__bf16)b.w;
  return r;
}

// ---------------- K0: graph start offsets from sorted batch ----------------
__global__ void k_offsets(const int* __restrict__ batch, int* __restrict__ starts) {
  int i = blockIdx.x * 256 + threadIdx.x;
  if (i >= N_NODES) return;
  int bi = batch[i];
  if (i == 0) {
    for (int g = 0; g <= bi; ++g) starts[g] = 0;
  } else {
    int bp = batch[i - 1];
    for (int g = bp + 1; g <= bi; ++g) starts[g] = i;
  }
  if (i == N_NODES - 1) {
    for (int g = bi + 1; g <= N_GRAPHS; ++g) starts[g] = N_NODES;
  }
}

// ------- K1: pack weights into MFMA B-fragment order (bf16) ----------------
// frag f, lane l, elem e -> B[k][j], k = ks*32+(l>>4)*8+e, j = jt*16+(l&15)
// w1a: f=jt*4+ks (jt<4,ks<4; W1 rows 0..127)
// wg1: f=jt*8+ks (jt<16,ks<8); wg2: f=jt*8+ks (jt<8,ks<8)
__global__ void k_prep(const float* __restrict__ W1, const float* __restrict__ Wg1,
                       const float* __restrict__ Wg2, unsigned short* __restrict__ w1af,
                       unsigned short* __restrict__ wg1f, unsigned short* __restrict__ wg2f) {
  int idx = blockIdx.x * 256 + threadIdx.x;
  if (idx < 8192) {
    int f = idx >> 9, lane = (idx >> 3) & 63, e = idx & 7;
    int jt = f >> 2, ks = f & 3;
    int k = ks * 32 + (lane >> 4) * 8 + e, j = jt * 16 + (lane & 15);
    w1af[idx] = f2bfu(W1[k * 64 + j]);
  } else if (idx < 73728) {
    int i2 = idx - 8192;
    int f = i2 >> 9, lane = (i2 >> 3) & 63, e = i2 & 7;
    int jt = f >> 3, ks = f & 7;
    int k = ks * 32 + (lane >> 4) * 8 + e, j = jt * 16 + (lane & 15);
    wg1f[i2] = f2bfu(Wg1[k * 256 + j]);
  } else if (idx < 106496) {
    int i3 = idx - 73728;
    int f = i3 >> 9, lane = (i3 >> 3) & 63, e = i3 & 7;
    int jt = f >> 3, ks = f & 7;
    int k = ks * 32 + (lane >> 4) * 8 + e, j = jt * 16 + (lane & 15);
    wg2f[i3] = f2bfu(Wg2[k * 128 + j]);
  }
}

// ------- K3: fused per-graph scores (MFMA) + segment softmax + pool --------
__global__ __launch_bounds__(256) void k_main(
    const float* __restrict__ x, const float* __restrict__ u,
    const float* __restrict__ W1, const float* __restrict__ b1,
    const float* __restrict__ W2, const int* __restrict__ starts,
    const unsigned short* __restrict__ w1af,
    float* __restrict__ pooled, float* __restrict__ attn) {
  __shared__ alignas(16) unsigned short x_lds[CAPX * 136];  // stride 136 bf16 (pad 8) for bank spread
  __shared__ float sc_lds[CAPS];
  __shared__ float uscore[64];
  __shared__ float fscr[256];
  __shared__ float wred[4];

  const int t = threadIdx.x;
  const int lane = t & 63;
  const int wv = t >> 6;
  const int l15 = lane & 15;
  const int l4 = lane >> 4;

  // loop-invariant: W1a fragments (16 x bf16x8) and per-lane W2
  bf16x8 w1f[4][4];
#pragma unroll
  for (int jt = 0; jt < 4; ++jt)
#pragma unroll
    for (int ks = 0; ks < 4; ++ks)
      w1f[jt][ks] = *(const bf16x8*)&w1af[((jt * 4 + ks) * 64 + lane) * 8];
  float w2r[4];
#pragma unroll
  for (int jt = 0; jt < 4; ++jt) w2r[jt] = W2[jt * 16 + l15];

  for (int g = blockIdx.x; g < N_GRAPHS; g += gridDim.x) {
    const int s = starts[g];
    const int cnt = starts[g + 1] - s;
    if (cnt > 0) {
      // Uscore = b1 + u[g] @ W1[128:256]  (b2 cancels in softmax, dropped)
      {
        const int j = t & 63, kq = t >> 6;
        const float* up = u + (size_t)g * 128 + kq * 32;
        const float* wp = W1 + (size_t)(128 + kq * 32) * 64 + j;
        float p = 0.f;
#pragma unroll 8
        for (int k = 0; k < 32; ++k) p += up[k] * wp[k * 64];
        fscr[t] = p;
      }
      __syncthreads();
      if (t < 64) uscore[t] = b1[t] + fscr[t] + fscr[64 + t] + fscr[128 + t] + fscr[192 + t];
      __syncthreads();

      // ---- pass 1: per-node scores via 16x16x32 bf16 MFMA ----
      const int nch = (cnt + 63) >> 6;
      for (int c = 0; c < nch; ++c) {
        const int tb = c * 64 + wv * 16;  // this wave's 16-node tile
        if (tb < cnt) {
          const int rl = tb + l15;                 // A-frag row (node, local)
          const int rc = rl < cnt ? rl : cnt - 1;  // clamp OOB rows
          const float* xp = x + (size_t)(s + rc) * 128 + l4 * 8;
          const bool st = (rl < cnt) && (rl < CAPX);
          f32x4 a0 = {0,0,0,0}, a1 = {0,0,0,0}, a2 = {0,0,0,0}, a3 = {0,0,0,0};
#pragma unroll
          for (int ks = 0; ks < 4; ++ks) {
            float4 v0 = *(const float4*)(xp + ks * 32);
            float4 v1 = *(const float4*)(xp + ks * 32 + 4);
            bf16x8 a = pack8(v0, v1);
            if (st) *(bf16x8*)&x_lds[rl * 136 + ks * 32 + l4 * 8] = a;  // stage for pass 2
            a0 = __builtin_amdgcn_mfma_f32_16x16x32_bf16(a, w1f[0][ks], a0, 0, 0, 0);
            a1 = __builtin_amdgcn_mfma_f32_16x16x32_bf16(a, w1f[1][ks], a1, 0, 0, 0);
            a2 = __builtin_amdgcn_mfma_f32_16x16x32_bf16(a, w1f[2][ks], a2, 0, 0, 0);
            a3 = __builtin_amdgcn_mfma_f32_16x16x32_bf16(a, w1f[3][ks], a3, 0, 0, 0);
          }
          // epilogue: relu(h + uscore) . W2, reduce over the 64 j spread across 16 lanes
          const float us0 = uscore[l15], us1 = uscore[16 + l15];
          const float us2 = uscore[32 + l15], us3 = uscore[48 + l15];
          float sc[4];
#pragma unroll
          for (int r = 0; r < 4; ++r) {
            float v = fmaxf(a0[r] + us0, 0.f) * w2r[0] +
                      fmaxf(a1[r] + us1, 0.f) * w2r[1] +
                      fmaxf(a2[r] + us2, 0.f) * w2r[2] +
                      fmaxf(a3[r] + us3, 0.f) * w2r[3];
            v += __shfl_xor(v, 1);
            v += __shfl_xor(v, 2);
            v += __shfl_xor(v, 4);
            v += __shfl_xor(v, 8);
            sc[r] = v;
          }
#pragma unroll
          for (int r = 0; r < 4; ++r) {
            if (l15 == r) {  // one writer per row; D row = l4*4 + r
              int row = tb + l4 * 4 + r;
              if (row < cnt) {
                if (row < CAPS) sc_lds[row] = sc[r];
                else attn[s + row] = sc[r];  // rare overflow: raw score to global temp
              }
            }
          }
        }
      }
      __syncthreads();

      // ---- segment max ----
      float lm = NEG_INF;
      for (int n = t; n < cnt; n += 256)
        lm = fmaxf(lm, (n < CAPS) ? sc_lds[n] : attn[s + n]);
#pragma unroll
      for (int off = 32; off; off >>= 1) lm = fmaxf(lm, __shfl_xor(lm, off));
      if (lane == 0) wred[wv] = lm;
      __syncthreads();
      const float m = fmaxf(fmaxf(wred[0], wred[1]), fmaxf(wred[2], wred[3]));
      __syncthreads();
      // ---- segment sum of exp ----
      float ls = 0.f;
      for (int n = t; n < cnt; n += 256)
        ls += __expf(((n < CAPS) ? sc_lds[n] : attn[s + n]) - m);
#pragma unroll
      for (int off = 32; off; off >>= 1) ls += __shfl_xor(ls, off);
      if (lane == 0) wred[wv] = ls;
      __syncthreads();
      const float rd = 1.f / (wred[0] + wred[1] + wred[2] + wred[3]);
      // ---- attn write (output) + keep in LDS for pooling ----
      for (int n = t; n < cnt; n += 256) {
        float sv = (n < CAPS) ? sc_lds[n] : attn[s + n];
        float a = __expf(sv - m) * rd;
        attn[s + n] = a;
        if (n < CAPS) sc_lds[n] = a;
      }
      __syncthreads();
      // ---- pass 2: pooled[g] = sum_n attn[n] * x[n] (x from LDS) ----
      {
        const int f = t & 127, half = t >> 7;
        float acc = 0.f;
        for (int n = half; n < cnt; n += 2) {
          float a = (n < CAPS) ? sc_lds[n] : attn[s + n];
          float xv = (n < CAPX) ? bfu2f(x_lds[n * 136 + f])
                                : x[(size_t)(s + n) * 128 + f];
          acc += a * xv;
        }
        fscr[t] = acc;
      }
      __syncthreads();
      if (t < 128) pooled[(size_t)g * 128 + t] = fscr[t] + fscr[128 + t];
    } else {
      if (t < 128) pooled[(size_t)g * 128 + t] = 0.f;  // empty segment
    }
    __syncthreads();
  }
}

// ------- K4: out = relu([u,pooled]@Wg1+bg1)@Wg2+bg2 (MFMA, 32 rows/block) ---
__global__ __launch_bounds__(256) void k_final(
    const float* __restrict__ u, const float* __restrict__ pooled,
    const unsigned short* __restrict__ wg1f, const unsigned short* __restrict__ wg2f,
    const float* __restrict__ bg1, const float* __restrict__ bg2,
    float* __restrict__ out) {
  __shared__ alignas(16) unsigned short x1[32 * 272];  // stride 272 bf16 (pad 16)
  __shared__ alignas(16) unsigned short hL[32 * 272];
  __shared__ float bg1s[256];
  __shared__ float bg2s[128];
  const int t = threadIdx.x;
  const int lane = t & 63;
  const int wv = t >> 6;
  const int l15 = lane & 15;
  const int l4 = lane >> 4;
  const int g0 = blockIdx.x * 32;

  bg1s[t] = bg1[t];
  if (t < 128) bg2s[t] = bg2[t];
  for (int idx = t; idx < 32 * 32; idx += 256) {
    int row = idx >> 5, c0 = (idx & 31) * 8;
    const float* src = (c0 < 128) ? (u + (size_t)(g0 + row) * 128 + c0)
                                  : (pooled + (size_t)(g0 + row) * 128 + (c0 - 128));
    float4 v0 = *(const float4*)src;
    float4 v1 = *(const float4*)(src + 4);
    *(bf16x8*)&x1[row * 272 + c0] = pack8(v0, v1);
  }
  __syncthreads();

  const int rt = (wv >> 1) * 16;  // row tile: waves {0,1}->rows 0..15, {2,3}->16..31
  const int jh = wv & 1;          // j-half split between wave pairs
  // GEMM1: H = relu(X1 @ Wg1 + bg1), K=256
  for (int jt = jh * 8; jt < jh * 8 + 8; ++jt) {
    f32x4 acc = {0,0,0,0};
#pragma unroll
    for (int ks = 0; ks < 8; ++ks) {
      bf16x8 b = *(const bf16x8*)&wg1f[((jt * 8 + ks) * 64 + lane) * 8];
      bf16x8 a = *(const bf16x8*)&x1[(rt + l15) * 272 + ks * 32 + l4 * 8];
      acc = __builtin_amdgcn_mfma_f32_16x16x32_bf16(a, b, acc, 0, 0, 0);
    }
    const int j = jt * 16 + l15;
#pragma unroll
    for (int r = 0; r < 4; ++r)
      hL[(rt + l4 * 4 + r) * 272 + j] = f2bfu(fmaxf(acc[r] + bg1s[j], 0.f));
  }
  __syncthreads();
  // GEMM2: out = H @ Wg2 + bg2, K=256
  for (int jt = jh * 4; jt < jh * 4 + 4; ++jt) {
    f32x4 acc = {0,0,0,0};
#pragma unroll
    for (int ks = 0; ks < 8; ++ks) {
      bf16x8 b = *(const bf16x8*)&wg2f[((jt * 8 + ks) * 64 + lane) * 8];
      bf16x8 a = *(const bf16x8*)&hL[(rt + l15) * 272 + ks * 32 + l4 * 8];
      acc = __builtin_amdgcn_mfma_f32_16x16x32_bf16(a, b, acc, 0, 0, 0);
    }
    const int j = jt * 16 + l15;
#pragma unroll
    for (int r = 0; r < 4; ++r)
      out[(size_t)(g0 + rt + l4 * 4 + r) * 128 + j] = acc[r] + bg2s[j];
  }
}

extern "C" void kernel_launch(void* const* d_in, const int* in_sizes, int n_in,
                              void* d_out, int out_size, void* d_ws, size_t ws_size,
                              hipStream_t stream) {
  const float* x     = (const float*)d_in[0];
  const float* u     = (const float*)d_in[3];
  const int*   batch = (const int*)d_in[4];
  const float* W1    = (const float*)d_in[5];
  const float* b1    = (const float*)d_in[6];
  const float* W2    = (const float*)d_in[7];
  // b2 (d_in[8]) cancels inside softmax — unused
  const float* Wg1   = (const float*)d_in[9];
  const float* bg1   = (const float*)d_in[10];
  const float* Wg2   = (const float*)d_in[11];
  const float* bg2   = (const float*)d_in[12];

  char* ws = (char*)d_ws;
  int* starts          = (int*)(ws);                       // 16385 ints = 65540 B
  unsigned short* w1af = (unsigned short*)(ws + 66048);    // 8192  bf16 = 16 KiB
  unsigned short* wg1f = (unsigned short*)(ws + 82432);    // 65536 bf16 = 128 KiB
  unsigned short* wg2f = (unsigned short*)(ws + 213504);   // 32768 bf16 = 64 KiB
  float* pooled        = (float*)(ws + 279040);            // 16384*128 f32 = 8 MiB
  float* outp = (float*)d_out;
  float* attn = (float*)d_out + (size_t)N_GRAPHS * 128;    // outputs: [out | attn]

  k_offsets<<<(N_NODES + 255) / 256, 256, 0, stream>>>(batch, starts);
  k_prep<<<(106496 + 255) / 256, 256, 0, stream>>>(W1, Wg1, Wg2, w1af, wg1f, wg2f);
  k_main<<<2048, 256, 0, stream>>>(x, u, W1, b1, W2, starts, w1af, pooled, attn);
  k_final<<<N_GRAPHS / 32, 256, 0, stream>>>(u, pooled, wg1f, wg2f, bg1, bg2, outp);
}